// Round 8
// baseline (153.444 us; speedup 1.0000x reference)
//
#include <hip/hip_runtime.h>

#define BB 512
#define SS 512
#define TT 64
#define TSTRIDE 66   // transitions is (66,66)

typedef _Float16 h2 __attribute__((ext_vector_type(2)));

static __device__ __forceinline__ float first_lane(float v) {
    return __int_as_float(__builtin_amdgcn_readfirstlane(__float_as_int(v)));
}
static __device__ __forceinline__ unsigned pk_f16(float a, float b) {
    return __builtin_bit_cast(unsigned, __builtin_amdgcn_cvt_pkrtz(a, b));
}
static __device__ __forceinline__ h2 as_h2(unsigned u) {
    return __builtin_bit_cast(h2, u);
}
static __device__ __forceinline__ unsigned bperm(int addr, unsigned v) {
    return (unsigned)__builtin_amdgcn_ds_bpermute(addr, (int)v);
}
#define FDOT2(a, b, c) __builtin_amdgcn_fdot2((a), (b), (c), false)
#define DPPF(v, ctrl) __int_as_float(__builtin_amdgcn_mov_dpp(__float_as_int(v), (ctrl), 0xF, 0xF, true))
#define DPPU(v, ctrl) ((unsigned)__builtin_amdgcn_mov_dpp((int)(v), (ctrl), 0xF, 0xF, true))

#define DO32(F) F(0) F(1) F(2) F(3) F(4) F(5) F(6) F(7) \
                F(8) F(9) F(10) F(11) F(12) F(13) F(14) F(15) \
                F(16) F(17) F(18) F(19) F(20) F(21) F(22) F(23) \
                F(24) F(25) F(26) F(27) F(28) F(29) F(30) F(31)

// One wave per batch, lane j owns p[j] = exp(score[j] - m0c) (anchored prob).
// R7 lesson: 535cy/step = exp + LDS write->read round trip (~240cy) + log on
// the serial chain. R8: (1) product-form recurrence removes exp/log from the
// loop: p' = (sum[j]/sum[0]) * g[j], g = exp(ee - ee0 - 4) precomputed from
// the emission ring 8 steps ahead; log(sum[0]) accumulates on a SIDE chain.
// (2) p broadcast via register butterfly: DPP (xor1, xor2, xor7, xor15, xor8
// via quad_perm/half_mirror/mirror) + 24 pipelined ds_bpermute for lanes
// j^16/j^32/j^48 — one LDS latency instead of two, no write->read serialization.
// E columns are loaded pre-permuted so slot k pairs with delivery order:
// row(word w, half h) = j ^ (b<<4) ^ mb[k>>1] ^ ((k&1)<<1) ^ h,
// w = 8b + k, mb = {0,7,15,8}.
__global__ __launch_bounds__(64)
__attribute__((amdgpu_waves_per_eu(1, 1)))
void crf_fused_kernel(
    const float* __restrict__ emissions,   // [B,S,T]
    const int*   __restrict__ tags,        // [B,S]
    const float* __restrict__ mask,        // [B,S]
    const float* __restrict__ trans,       // [66,66]
    float* __restrict__ diff_out)          // [B] = logZ - gold
{
    __shared__ unsigned EQ[32][64];        // 8 KB staging (blocks remat)

    const int b = blockIdx.x;
    const int j = threadIdx.x;   // 0..63

    const float* em = emissions + (size_t)b * SS * TT;
    const float* mk = mask + (size_t)b * SS;

    // ---- E init: f16-packed, pre-permuted per lane ----
    #pragma unroll
    for (int w = 0; w < 32; ++w) {
        int k = w & 7, bb = w >> 3;
        int mbv = (0x8F70 >> ((k >> 1) * 4)) & 0xF;   // {0,7,15,8}
        int xv0 = (bb << 4) ^ mbv ^ ((k & 1) << 1);
        int r0 = j ^ xv0;
        int r1 = r0 ^ 1;
        EQ[w][j] = pk_f16(__expf(trans[r0 * TSTRIDE + j]),
                          __expf(trans[r1 * TSTRIDE + j]));
    }
    __syncthreads();

#define CDECL(K) const unsigned c##K = EQ[K][j];
    DO32(CDECL)
#undef CDECL

    const int a16 = ((j ^ 16) << 2);
    const int a32 = ((j ^ 32) << 2);
    const int a48 = ((j ^ 48) << 2);

    // len = sum(mask row) — mask is a 0/1 length-prefix, len in [256,512]
    float msum = 0.f;
    #pragma unroll
    for (int t = 0; t < 8; ++t) msum += mk[j + 64 * t];
    #pragma unroll
    for (int off = 32; off; off >>= 1) msum += __shfl_xor(msum, off);
    const int len = (int)(first_lane(msum) + 0.5f);

    const float estop = __expf(trans[65 * TSTRIDE + j]);

    // bootstrap: score0 = em[0,j] + trans[j, start]; p = exp(score0 - m0c0)
    float sc0 = em[j] + trans[j * TSTRIDE + TT];
    const float m0c0 = first_lane(sc0) + 4.0f;
    float p = __expf(sc0 - m0c0);

    float L2 = 0.f;   // sum of log2(sum_0)  (side chain)
    float Lc = 0.f;   // sum of (ee_0 + 4)   (side chain)

#define GPREP(RK, SVAL, GOUT) do { \
        float ee_ = ((SVAL) < len) ? (RK) : 0.0f; \
        float e0_ = first_lane(ee_); \
        GOUT = __expf(ee_ - e0_ - 4.0f); \
        Lc += e0_ + 4.0f; \
    } while (0)

#define STEP(GK) do { \
        float pn_ = DPPF(p, 0xB1); \
        unsigned W0 = pk_f16(p, pn_); \
        unsigned W1 = DPPU(W0, 0x4E); \
        unsigned W2 = DPPU(W0, 0x141); \
        unsigned W3 = DPPU(W1, 0x141); \
        unsigned W4 = DPPU(W0, 0x140); \
        unsigned W5 = DPPU(W1, 0x140); \
        unsigned W6 = DPPU(W4, 0x141); \
        unsigned W7 = DPPU(W5, 0x141); \
        unsigned X10 = bperm(a16, W0), X11 = bperm(a16, W1); \
        unsigned X12 = bperm(a16, W2), X13 = bperm(a16, W3); \
        unsigned X14 = bperm(a16, W4), X15 = bperm(a16, W5); \
        unsigned X16 = bperm(a16, W6), X17 = bperm(a16, W7); \
        unsigned X20 = bperm(a32, W0), X21 = bperm(a32, W1); \
        unsigned X22 = bperm(a32, W2), X23 = bperm(a32, W3); \
        unsigned X24 = bperm(a32, W4), X25 = bperm(a32, W5); \
        unsigned X26 = bperm(a32, W6), X27 = bperm(a32, W7); \
        unsigned X30 = bperm(a48, W0), X31 = bperm(a48, W1); \
        unsigned X32 = bperm(a48, W2), X33 = bperm(a48, W3); \
        unsigned X34 = bperm(a48, W4), X35 = bperm(a48, W5); \
        unsigned X36 = bperm(a48, W6), X37 = bperm(a48, W7); \
        float a0_ = 0.f, a1_ = 0.f, a2_ = 0.f, a3_ = 0.f; \
        a0_ = FDOT2(as_h2(W0),  as_h2(c0),  a0_); \
        a1_ = FDOT2(as_h2(W1),  as_h2(c1),  a1_); \
        a2_ = FDOT2(as_h2(W2),  as_h2(c2),  a2_); \
        a3_ = FDOT2(as_h2(W3),  as_h2(c3),  a3_); \
        a0_ = FDOT2(as_h2(W4),  as_h2(c4),  a0_); \
        a1_ = FDOT2(as_h2(W5),  as_h2(c5),  a1_); \
        a2_ = FDOT2(as_h2(W6),  as_h2(c6),  a2_); \
        a3_ = FDOT2(as_h2(W7),  as_h2(c7),  a3_); \
        a0_ = FDOT2(as_h2(X10), as_h2(c8),  a0_); \
        a1_ = FDOT2(as_h2(X11), as_h2(c9),  a1_); \
        a2_ = FDOT2(as_h2(X12), as_h2(c10), a2_); \
        a3_ = FDOT2(as_h2(X13), as_h2(c11), a3_); \
        a0_ = FDOT2(as_h2(X14), as_h2(c12), a0_); \
        a1_ = FDOT2(as_h2(X15), as_h2(c13), a1_); \
        a2_ = FDOT2(as_h2(X16), as_h2(c14), a2_); \
        a3_ = FDOT2(as_h2(X17), as_h2(c15), a3_); \
        a0_ = FDOT2(as_h2(X20), as_h2(c16), a0_); \
        a1_ = FDOT2(as_h2(X21), as_h2(c17), a1_); \
        a2_ = FDOT2(as_h2(X22), as_h2(c18), a2_); \
        a3_ = FDOT2(as_h2(X23), as_h2(c19), a3_); \
        a0_ = FDOT2(as_h2(X24), as_h2(c20), a0_); \
        a1_ = FDOT2(as_h2(X25), as_h2(c21), a1_); \
        a2_ = FDOT2(as_h2(X26), as_h2(c22), a2_); \
        a3_ = FDOT2(as_h2(X27), as_h2(c23), a3_); \
        a0_ = FDOT2(as_h2(X30), as_h2(c24), a0_); \
        a1_ = FDOT2(as_h2(X31), as_h2(c25), a1_); \
        a2_ = FDOT2(as_h2(X32), as_h2(c26), a2_); \
        a3_ = FDOT2(as_h2(X33), as_h2(c27), a3_); \
        a0_ = FDOT2(as_h2(X34), as_h2(c28), a0_); \
        a1_ = FDOT2(as_h2(X35), as_h2(c29), a1_); \
        a2_ = FDOT2(as_h2(X36), as_h2(c30), a2_); \
        a3_ = FDOT2(as_h2(X37), as_h2(c31), a3_); \
        float sum_ = (a0_ + a1_) + (a2_ + a3_); \
        float s0_ = first_lane(sum_); \
        L2 += __log2f(s0_); \
        p = (sum_ * (GK)) * __builtin_amdgcn_rcpf(s0_); \
    } while (0)

    // emission ring, depth 8 (rows 1..8)
    float r0 = em[1 * TT + j], r1 = em[2 * TT + j];
    float r2 = em[3 * TT + j], r3 = em[4 * TT + j];
    float r4 = em[5 * TT + j], r5 = em[6 * TT + j];
    float r6 = em[7 * TT + j], r7 = em[8 * TT + j];

    const float* pe = em + 9 * TT + j;
    int scur = 1;
    for (int it = 0; it < 62; ++it) {
        float n0 = pe[0],   n1 = pe[64],  n2 = pe[128], n3 = pe[192];
        float n4 = pe[256], n5 = pe[320], n6 = pe[384], n7 = pe[448];
        pe += 512;
        float g0, g1, g2, g3, g4, g5, g6, g7;
        GPREP(r0, scur + 0, g0); GPREP(r1, scur + 1, g1);
        GPREP(r2, scur + 2, g2); GPREP(r3, scur + 3, g3);
        GPREP(r4, scur + 4, g4); GPREP(r5, scur + 5, g5);
        GPREP(r6, scur + 6, g6); GPREP(r7, scur + 7, g7);
        STEP(g0); STEP(g1); STEP(g2); STEP(g3);
        STEP(g4); STEP(g5); STEP(g6); STEP(g7);
        scur += 8;
        r0 = n0; r1 = n1; r2 = n2; r3 = n3;
        r4 = n4; r5 = n5; r6 = n6; r7 = n7;
    }
    // tail: ring = rows 497..504; load rows 505..511; 15 steps
    {
        float t0 = pe[0],   t1 = pe[64],  t2 = pe[128], t3 = pe[192];
        float t4 = pe[256], t5 = pe[320], t6 = pe[384];
        float g0, g1, g2, g3, g4, g5, g6, g7, h0, h1, h2x, h3, h4, h5, h6;
        GPREP(r0, 497, g0); GPREP(r1, 498, g1); GPREP(r2, 499, g2);
        GPREP(r3, 500, g3); GPREP(r4, 501, g4); GPREP(r5, 502, g5);
        GPREP(r6, 503, g6); GPREP(r7, 504, g7);
        GPREP(t0, 505, h0); GPREP(t1, 506, h1); GPREP(t2, 507, h2x);
        GPREP(t3, 508, h3); GPREP(t4, 509, h4); GPREP(t5, 510, h5);
        GPREP(t6, 511, h6);
        STEP(g0); STEP(g1); STEP(g2); STEP(g3);
        STEP(g4); STEP(g5); STEP(g6); STEP(g7);
        STEP(h0); STEP(h1); STEP(h2x); STEP(h3);
        STEP(h4); STEP(h5); STEP(h6);
    }
#undef STEP
#undef GPREP

    // logZ = m0c_S + log(sum_j p[j] * exp(stop_j))
    const float m0cS = m0c0 + L2 * 0.69314718055994531f + Lc;
    float v = p * estop;
    #pragma unroll
    for (int off = 32; off; off >>= 1) v += __shfl_xor(v, off);
    float zres = m0cS + __logf(v);

    // ---- gold path ----
    const int* tg = tags + (size_t)b * SS;
    float acc = 0.f;
    for (int s = j; s < SS; s += 64) {
        if (s < len) {
            if (s > 0) {
                int curr = tg[s], prev = tg[s - 1];
                acc += trans[curr * TSTRIDE + prev] + em[s * TT + curr];
            } else {
                int t0_ = tg[0];
                acc += em[t0_] + trans[t0_ * TSTRIDE + TT];
            }
        }
    }
    #pragma unroll
    for (int off = 32; off; off >>= 1) acc += __shfl_xor(acc, off);
    if (j == 0) {
        int last = tg[len - 1];
        acc += trans[65 * TSTRIDE + last];
        diff_out[b] = zres - acc;
    }
}

__global__ __launch_bounds__(256) void crf_final_kernel(
    const float* __restrict__ diff,
    float* __restrict__ out)
{
    __shared__ float sdata[4];
    int t = threadIdx.x;
    float v = 0.f;
    for (int i = t; i < BB; i += 256) v += diff[i];
    #pragma unroll
    for (int off = 32; off; off >>= 1) v += __shfl_xor(v, off);
    if ((t & 63) == 0) sdata[t >> 6] = v;
    __syncthreads();
    if (t == 0) out[0] = (sdata[0] + sdata[1] + sdata[2] + sdata[3]) * (1.0f / BB);
}

extern "C" void kernel_launch(void* const* d_in, const int* in_sizes, int n_in,
                              void* d_out, int out_size, void* d_ws, size_t ws_size,
                              hipStream_t stream) {
    const float* emissions = (const float*)d_in[0];
    const int*   tags      = (const int*)d_in[1];
    const float* mask      = (const float*)d_in[2];
    const float* trans     = (const float*)d_in[3];
    float* out  = (float*)d_out;
    float* diff = (float*)d_ws;

    crf_fused_kernel<<<BB, 64, 0, stream>>>(emissions, tags, mask, trans, diff);
    crf_final_kernel<<<1, 256, 0, stream>>>(diff, out);
}

// Round 9
// 64.207 us; speedup vs baseline: 2.3898x; 2.3898x over previous
//
#include <hip/hip_runtime.h>

#define BB 512
#define SS 512
#define TT 64
#define TSTRIDE 66   // transitions is (66,66)
#define MID 256      // fwd: steps 1..255; bwd: steps 511..256

typedef _Float16 h2 __attribute__((ext_vector_type(2)));

static __device__ __forceinline__ float first_lane(float v) {
    return __int_as_float(__builtin_amdgcn_readfirstlane(__float_as_int(v)));
}
static __device__ __forceinline__ unsigned pk_f16(float a, float b) {
    return __builtin_bit_cast(unsigned, __builtin_amdgcn_cvt_pkrtz(a, b));
}
static __device__ __forceinline__ h2 as_h2(unsigned u) {
    return __builtin_bit_cast(h2, u);
}
#define FDOT2(a, b, c) __builtin_amdgcn_fdot2((a), (b), (c), false)

#define DO32(F) F(0) F(1) F(2) F(3) F(4) F(5) F(6) F(7) \
                F(8) F(9) F(10) F(11) F(12) F(13) F(14) F(15) \
                F(16) F(17) F(18) F(19) F(20) F(21) F(22) F(23) \
                F(24) F(25) F(26) F(27) F(28) F(29) F(30) F(31)

// Meet-in-the-middle: block 2b = forward half of batch b (steps 1..255,
// always unmasked since len>=256), block 2b+1 = backward half (steps
// 511..256, u-recurrence u'[i] = LSE_j(tt[i][j]+ee[j]+u[j]), emission folded
// inside the exp). Step skeleton = R7's proven LDS write->read broadcast
// (535 cy/step); sequential depth halves 511 -> 256.
__global__ __launch_bounds__(64)
__attribute__((amdgpu_waves_per_eu(1, 1)))
void crf_scan2_kernel(
    const float* __restrict__ emissions,   // [B,S,T]
    const float* __restrict__ mask,        // [B,S]
    const float* __restrict__ trans,       // [66,66]
    float* __restrict__ ws_state)          // [B][128]: F[64] then U[64]
{
    __shared__ unsigned EQ[32][64];        // 8 KB E-fragment staging
    __shared__ uint4 PLv[8];               // p broadcast buffer (f16 x64)

    const int blk = blockIdx.x;
    const int b   = blk >> 1;
    const int dir = blk & 1;
    const int j   = threadIdx.x;   // 0..63

    const float* em = emissions + (size_t)b * SS * TT;
    const float* mk = mask + (size_t)b * SS;
    unsigned short* PL = (unsigned short*)PLv;
    const uint4* PV = (const uint4*)PLv;

    // ---- E fragments: fwd lane j = column j; bwd lane i = row i ----
    if (dir == 0) {
        #pragma unroll
        for (int w = 0; w < 32; ++w)
            EQ[w][j] = pk_f16(__expf(trans[(2 * w) * TSTRIDE + j]),
                              __expf(trans[(2 * w + 1) * TSTRIDE + j]));
    } else {
        #pragma unroll
        for (int w = 0; w < 32; ++w)
            EQ[w][j] = pk_f16(__expf(trans[j * TSTRIDE + 2 * w]),
                              __expf(trans[j * TSTRIDE + 2 * w + 1]));
    }
    __syncthreads();

#define CDECL(K) const unsigned c##K = EQ[K][j];
    DO32(CDECL)
#undef CDECL

#define DOT4(D, CA, CB, CC, CD) \
    a0_ = FDOT2(as_h2((D).x), as_h2(CA), a0_); \
    a1_ = FDOT2(as_h2((D).y), as_h2(CB), a1_); \
    a2_ = FDOT2(as_h2((D).z), as_h2(CC), a2_); \
    a3_ = FDOT2(as_h2((D).w), as_h2(CD), a3_);

    // PRE folds inside the exp (bwd emission), POST adds after log (fwd).
#define STEPC(PRE, POST, CADD) do { \
        float m0c = first_lane(sc) + (CADD); \
        float p   = __expf(sc + (PRE) - m0c); \
        PL[j] = (unsigned short)(pk_f16(p, p) & 0xFFFF); \
        uint4 d0 = PV[0], d1 = PV[1], d2 = PV[2], d3 = PV[3]; \
        uint4 d4 = PV[4], d5 = PV[5], d6 = PV[6], d7 = PV[7]; \
        float a0_ = 0.f, a1_ = 0.f, a2_ = 0.f, a3_ = 0.f; \
        DOT4(d0, c0,  c1,  c2,  c3)  DOT4(d1, c4,  c5,  c6,  c7) \
        DOT4(d2, c8,  c9,  c10, c11) DOT4(d3, c12, c13, c14, c15) \
        DOT4(d4, c16, c17, c18, c19) DOT4(d5, c20, c21, c22, c23) \
        DOT4(d6, c24, c25, c26, c27) DOT4(d7, c28, c29, c30, c31) \
        sc = m0c + __logf((a0_ + a1_) + (a2_ + a3_)) + (POST); \
    } while (0)

    float sc;
    if (dir == 0) {
        // ---------- forward: steps 1..255, no mask ----------
        sc = em[j] + trans[j * TSTRIDE + TT];   // score0 (mask[0]==1)
        float r0 = em[1 * TT + j], r1 = em[2 * TT + j];
        float r2 = em[3 * TT + j], r3 = em[4 * TT + j];
        float r4 = em[5 * TT + j], r5 = em[6 * TT + j];
        float r6 = em[7 * TT + j], r7 = em[8 * TT + j];
        const float* pe = em + 9 * TT + j;
        for (int it = 0; it < 31; ++it) {       // steps 1..248
            float n0 = pe[0],   n1 = pe[64],  n2 = pe[128], n3 = pe[192];
            float n4 = pe[256], n5 = pe[320], n6 = pe[384], n7 = pe[448];
            pe += 512;
            STEPC(0.0f, r0, 4.0f); STEPC(0.0f, r1, 4.0f);
            STEPC(0.0f, r2, 4.0f); STEPC(0.0f, r3, 4.0f);
            STEPC(0.0f, r4, 4.0f); STEPC(0.0f, r5, 4.0f);
            STEPC(0.0f, r6, 4.0f); STEPC(0.0f, r7, 4.0f);
            r0 = n0; r1 = n1; r2 = n2; r3 = n3;
            r4 = n4; r5 = n5; r6 = n6; r7 = n7;
        }
        // steps 249..255 (ring rows 249..255 in r0..r6)
        STEPC(0.0f, r0, 4.0f); STEPC(0.0f, r1, 4.0f);
        STEPC(0.0f, r2, 4.0f); STEPC(0.0f, r3, 4.0f);
        STEPC(0.0f, r4, 4.0f); STEPC(0.0f, r5, 4.0f);
        STEPC(0.0f, r6, 4.0f);
        ws_state[(size_t)b * 128 + j] = sc;
    } else {
        // ---------- backward: steps 511..256 ----------
        // len = sum(mask row), len in [256,512]
        float msum = 0.f;
        #pragma unroll
        for (int t = 0; t < 8; ++t) msum += mk[j + 64 * t];
        #pragma unroll
        for (int off = 32; off; off >>= 1) msum += __shfl_xor(msum, off);
        const int len = (int)(first_lane(msum) + 0.5f);

        sc = trans[65 * TSTRIDE + j];           // u_511 = stop vector
        float r0 = em[511 * TT + j], r1 = em[510 * TT + j];
        float r2 = em[509 * TT + j], r3 = em[508 * TT + j];
        float r4 = em[507 * TT + j], r5 = em[506 * TT + j];
        float r6 = em[505 * TT + j], r7 = em[504 * TT + j];
        const float* pe = em + 503 * TT + j;
        int scur = 511;
#define BEE(RK, SV) (((SV) < len) ? (RK) : 0.0f)
        for (int it = 0; it < 31; ++it) {       // steps 511..264
            float n0 = pe[0],    n1 = pe[-64],  n2 = pe[-128], n3 = pe[-192];
            float n4 = pe[-256], n5 = pe[-320], n6 = pe[-384], n7 = pe[-448];
            pe -= 512;
            STEPC(BEE(r0, scur - 0), 0.0f, 5.0f);
            STEPC(BEE(r1, scur - 1), 0.0f, 5.0f);
            STEPC(BEE(r2, scur - 2), 0.0f, 5.0f);
            STEPC(BEE(r3, scur - 3), 0.0f, 5.0f);
            STEPC(BEE(r4, scur - 4), 0.0f, 5.0f);
            STEPC(BEE(r5, scur - 5), 0.0f, 5.0f);
            STEPC(BEE(r6, scur - 6), 0.0f, 5.0f);
            STEPC(BEE(r7, scur - 7), 0.0f, 5.0f);
            scur -= 8;
            r0 = n0; r1 = n1; r2 = n2; r3 = n3;
            r4 = n4; r5 = n5; r6 = n6; r7 = n7;
        }
        // steps 263..256 (ring rows 263..256 in r0..r7)
        STEPC(BEE(r0, 263), 0.0f, 5.0f); STEPC(BEE(r1, 262), 0.0f, 5.0f);
        STEPC(BEE(r2, 261), 0.0f, 5.0f); STEPC(BEE(r3, 260), 0.0f, 5.0f);
        STEPC(BEE(r4, 259), 0.0f, 5.0f); STEPC(BEE(r5, 258), 0.0f, 5.0f);
        STEPC(BEE(r6, 257), 0.0f, 5.0f); STEPC(BEE(r7, 256), 0.0f, 5.0f);
#undef BEE
        ws_state[(size_t)b * 128 + 64 + j] = sc;
    }
#undef STEPC
#undef DOT4
}

// Per-batch wave: logZ = LSE_j(F[j]+U[j]), gold path, diff = logZ - gold.
__global__ __launch_bounds__(64) void crf_combine_kernel(
    const float* __restrict__ emissions,
    const int*   __restrict__ tags,
    const float* __restrict__ mask,
    const float* __restrict__ trans,
    const float* __restrict__ ws_state,
    float* __restrict__ diff_out)
{
    const int b = blockIdx.x;
    const int j = threadIdx.x;
    const float* em = emissions + (size_t)b * SS * TT;
    const float* mk = mask + (size_t)b * SS;

    float v = ws_state[(size_t)b * 128 + j] + ws_state[(size_t)b * 128 + 64 + j];
    float m = v;
    #pragma unroll
    for (int off = 32; off; off >>= 1) m = fmaxf(m, __shfl_xor(m, off));
    float e = __expf(v - m);
    #pragma unroll
    for (int off = 32; off; off >>= 1) e += __shfl_xor(e, off);
    float zres = m + __logf(e);

    // len
    float msum = 0.f;
    #pragma unroll
    for (int t = 0; t < 8; ++t) msum += mk[j + 64 * t];
    #pragma unroll
    for (int off = 32; off; off >>= 1) msum += __shfl_xor(msum, off);
    const int len = (int)(first_lane(msum) + 0.5f);

    // gold
    const int* tg = tags + (size_t)b * SS;
    float acc = 0.f;
    for (int s = j; s < SS; s += 64) {
        if (s < len) {
            if (s > 0) {
                int curr = tg[s], prev = tg[s - 1];
                acc += trans[curr * TSTRIDE + prev] + em[s * TT + curr];
            } else {
                int t0_ = tg[0];
                acc += em[t0_] + trans[t0_ * TSTRIDE + TT];
            }
        }
    }
    #pragma unroll
    for (int off = 32; off; off >>= 1) acc += __shfl_xor(acc, off);
    if (j == 0) {
        int last = tg[len - 1];
        acc += trans[65 * TSTRIDE + last];
        diff_out[b] = zres - acc;
    }
}

__global__ __launch_bounds__(256) void crf_final_kernel(
    const float* __restrict__ diff,
    float* __restrict__ out)
{
    __shared__ float sdata[4];
    int t = threadIdx.x;
    float v = 0.f;
    for (int i = t; i < BB; i += 256) v += diff[i];
    #pragma unroll
    for (int off = 32; off; off >>= 1) v += __shfl_xor(v, off);
    if ((t & 63) == 0) sdata[t >> 6] = v;
    __syncthreads();
    if (t == 0) out[0] = (sdata[0] + sdata[1] + sdata[2] + sdata[3]) * (1.0f / BB);
}

extern "C" void kernel_launch(void* const* d_in, const int* in_sizes, int n_in,
                              void* d_out, int out_size, void* d_ws, size_t ws_size,
                              hipStream_t stream) {
    const float* emissions = (const float*)d_in[0];
    const int*   tags      = (const int*)d_in[1];
    const float* mask      = (const float*)d_in[2];
    const float* trans     = (const float*)d_in[3];
    float* out  = (float*)d_out;
    float* ws_state = (float*)d_ws;             // 512*128 floats
    float* diff = ws_state + (size_t)BB * 128;  // 512 floats

    crf_scan2_kernel<<<2 * BB, 64, 0, stream>>>(emissions, mask, trans, ws_state);
    crf_combine_kernel<<<BB, 64, 0, stream>>>(emissions, tags, mask, trans,
                                              ws_state, diff);
    crf_final_kernel<<<1, 256, 0, stream>>>(diff, out);
}